// Round 1
// baseline (552.995 us; speedup 1.0000x reference)
//
#include <hip/hip_runtime.h>
#include <stdint.h>

typedef unsigned short ushort_t;
typedef __attribute__((ext_vector_type(8))) short short8;
typedef __attribute__((ext_vector_type(8))) unsigned short ushortx8;
typedef __attribute__((ext_vector_type(4))) float floatx4;

#define B_    32
#define C_    256
#define O_    256
#define HID_  65
#define HW_   4096
#define KDIM  2304          // C_ * 9
#define XP_H  66            // padded spatial edge
#define XPAD_ELEMS ((size_t)B_ * XP_H * XP_H * C_)   // 35,684,352 bf16
#define WAGG_ELEMS ((size_t)B_ * O_ * KDIM)          // 18,874,368 bf16

static __device__ __forceinline__ unsigned short f2bf(float f) {
  unsigned u = __float_as_uint(f);
  u += 0x7fffu + ((u >> 16) & 1u);        // RNE
  return (unsigned short)(u >> 16);
}

static __device__ __forceinline__ void gld_lds16(const void* g, void* l) {
  // async global->LDS, 16B/lane; LDS dest = wave-uniform base + lane*16
  __builtin_amdgcn_global_load_lds((__attribute__((address_space(1))) void*)(g),
                                   (__attribute__((address_space(3))) void*)(l),
                                   16, 0, 0);
}

// -------------------------------------------------------------- border ------
// zero only the pad borders of xpad (4.3 MB) instead of memsetting 71 MB.
// interior is fully overwritten by pad_kernel.
__global__ void border_kernel(ushort_t* __restrict__ xpad) {
  const int b = blockIdx.x, t = threadIdx.x;
  uint4 z = {0u, 0u, 0u, 0u};
  uint4* base = (uint4*)(xpad + (size_t)b * XP_H * XP_H * C_);
  // row stride = 66*256 shorts = 2112 uint4; w stride = 256 shorts = 32 uint4
  for (int i = t; i < 2112; i += 256) {            // rows h=0 and h=65
    base[i] = z;
    base[(size_t)65 * 2112 + i] = z;
  }
  for (int i = t; i < 64 * 32; i += 256) {         // cols w=0 and w=65, h=1..64
    const int h = 1 + (i >> 5), s = i & 31;
    base[(size_t)h * 2112 + s] = z;
    base[(size_t)h * 2112 + 65 * 32 + s] = z;
  }
}

// ----------------------------------------------------------------- pad ------
// xpad[b][h+1][w+1][c] (bf16, HWC) from x[b][c][h][w] (fp32, CHW), PLUS
// per-block pooling partials: partial[hwT][b*C+c] = sum over this tile's 64 hw.
// Rewritten: float4 loads (16 B/lane), LDS transpose tile [hw][c] (pad 65,
// all phases <=2-way bank alias), ushort8 stores (16 B/lane).
__global__ void pad_kernel(const float* __restrict__ x, ushort_t* __restrict__ xpad,
                           float* __restrict__ partial) {
  __shared__ float tileT[64][65];                  // [hw][c], 16.6 KB
  __shared__ float pool[4][64];
  const int hwT = blockIdx.x, cT = blockIdx.y, b = blockIdx.z;
  const int t = threadIdx.x;
  const int hw0 = hwT * 64, c0 = cT * 64;
  const float* src = x + ((size_t)(b * C_ + c0)) * HW_ + hw0;

  // load: 64c x 64hw = 1024 float4; 4 per thread. lanes sweep hw -> coalesced.
#pragma unroll
  for (int p = 0; p < 4; ++p) {
    const int flat = p * 256 + t;
    const int c = flat >> 4, h4 = (flat & 15) * 4;
    const float4 v = *(const float4*)(src + (size_t)c * HW_ + h4);
    tileT[h4 + 0][c] = v.x;                        // banks: (4*h4'+c)%32 -> 2-way
    tileT[h4 + 1][c] = v.y;
    tileT[h4 + 2][c] = v.z;
    tileT[h4 + 3][c] = v.w;
  }
  __syncthreads();

  // pooling: thread owns (qh,c); reads stride-1 in c -> 2-way, free.
  {
    const int c = t & 63, qh = t >> 6;
    float s = 0.f;
#pragma unroll
    for (int i = 0; i < 16; ++i) s += tileT[qh * 16 + i][c];
    pool[qh][c] = s;
  }
  __syncthreads();
  if (t < 64) {
    partial[(size_t)hwT * (B_ * C_) + b * C_ + c0 + t] =
        pool[0][t] + pool[1][t] + pool[2][t] + pool[3][t];
  }

  // store: thread reads 8 consecutive c at one hw (banks hw + 8*cg -> 2-way),
  // writes one ushort8 (16 B/lane; 8x128B segments per wave-inst).
#pragma unroll
  for (int p = 0; p < 2; ++p) {
    const int flat = p * 256 + t;
    const int hw = flat >> 3, cg = (flat & 7) * 8;
    ushortx8 v;
#pragma unroll
    for (int j = 0; j < 8; ++j) v[j] = f2bf(tileT[hw][cg + j]);
    const int h = (hw0 + hw) >> 6, w = (hw0 + hw) & 63;
    *(ushortx8*)(xpad + (((size_t)b * XP_H + (h + 1)) * XP_H + (w + 1)) * C_ + c0 + cg) = v;
  }
}

// ---------------------------------------------------------------- attn ------
// one block per b. reduce partials -> pooled; h = relu(pooled@w1^T);
// logits = h@w2^T + b2; softmax over K.
__global__ void attn_kernel(const float* __restrict__ partial,
                            const float* __restrict__ w1,
                            const float* __restrict__ w2,
                            const float* __restrict__ b2,
                            float* __restrict__ attn) {
  __shared__ float sp[C_];
  __shared__ float sh[HID_];
  const int b = blockIdx.x, t = threadIdx.x;
  {
    float s = 0.f;
#pragma unroll
    for (int i = 0; i < 64; ++i) s += partial[(size_t)i * (B_ * C_) + b * C_ + t];
    sp[t] = s * (1.f / 4096.f);
  }
  __syncthreads();
  if (t < HID_) {
    float a = 0.f;
    for (int c = 0; c < C_; ++c) a += sp[c] * w1[t * C_ + c];
    sh[t] = fmaxf(a, 0.f);
  }
  __syncthreads();
  float lg[4];
#pragma unroll
  for (int k = 0; k < 4; ++k) {
    float a = b2[k * O_ + t];
    for (int j = 0; j < HID_; ++j) a += sh[j] * w2[(k * O_ + t) * HID_ + j];
    lg[k] = a * 2.0f;                              // / TEMP (0.5)
  }
  float mx = fmaxf(fmaxf(lg[0], lg[1]), fmaxf(lg[2], lg[3]));
  float e0 = expf(lg[0] - mx), e1 = expf(lg[1] - mx);
  float e2 = expf(lg[2] - mx), e3 = expf(lg[3] - mx);
  float inv = 1.f / (e0 + e1 + e2 + e3);
  attn[(b * 4 + 0) * O_ + t] = e0 * inv;
  attn[(b * 4 + 1) * O_ + t] = e1 * inv;
  attn[(b * 4 + 2) * O_ + t] = e2 * inv;
  attn[(b * 4 + 3) * O_ + t] = e3 * inv;
}

// ----------------------------------------------------------------- agg ------
// wagg[b][o][tap*256+c] = sum_k attn[b,k,o]*weight[k,o,c,tap]
// Rewritten flat: one ushort8 chunk per thread, full-GPU grid, contiguous
// 16 B/lane stores (each (b,o) 4.6 KB row written contiguously by lanes).
// chunks = B*O*KDIM/8 = 2,359,296 = 9216 blocks x 256 threads exactly.
__global__ void agg_kernel(const float* __restrict__ attn,
                           const float* __restrict__ wt,
                           ushort_t* __restrict__ wagg) {
  const int u = blockIdx.x * 256 + threadIdx.x;
  const int rc = u % 288;                          // tap*32 + c8
  const int bo = u / 288;                          // b*256 + o
  const int o = bo & 255, b = bo >> 8;
  const int tap = rc >> 5, c = (rc & 31) * 8;
  const float a0 = attn[(b * 4 + 0) * O_ + o];
  const float a1 = attn[(b * 4 + 1) * O_ + o];
  const float a2 = attn[(b * 4 + 2) * O_ + o];
  const float a3 = attn[(b * 4 + 3) * O_ + o];
  const float* w0 = wt + ((size_t)(0 * O_ + o) * C_ + c) * 9 + tap;
  const float* w1 = wt + ((size_t)(1 * O_ + o) * C_ + c) * 9 + tap;
  const float* w2 = wt + ((size_t)(2 * O_ + o) * C_ + c) * 9 + tap;
  const float* w3 = wt + ((size_t)(3 * O_ + o) * C_ + c) * 9 + tap;
  ushortx8 v;
#pragma unroll
  for (int j = 0; j < 8; ++j) {
    const float s = a0 * w0[j * 9] + a1 * w1[j * 9] + a2 * w2[j * 9] + a3 * w3[j * 9];
    v[j] = f2bf(s);
  }
  *(ushortx8*)(wagg + (size_t)bo * KDIM + tap * 256 + c) = v;
}

// ---------------------------------------------------------------- gemm ------
// per block: one b, 128-o tile, 128-hw tile. K = 9 taps x 256 c, BK = 64
// (36 K-steps x 32 MFMA vs round-1's 72 x 16 — halves barrier-drain count).
// Rows are 64 shorts = 8 slots of 16B; physical slot = logical ^ (row & 7)
// keeps global_load_lds w=16 contiguity and <=2-way LDS bank aliasing.
__global__ __launch_bounds__(256) void gemm_kernel(const ushort_t* __restrict__ xpad,
                                                   const ushort_t* __restrict__ wagg,
                                                   float* __restrict__ out) {
  __shared__ short lA[128 * 64];                   // 16 KB
  __shared__ short lB[128 * 64];                   // 16 KB

  const int hwT = blockIdx.x;                      // 0..31
  const int oT  = blockIdx.y;                      // 0..1
  const int b   = blockIdx.z;                      // 0..31
  const int t    = threadIdx.x;
  const int lane = t & 63;
  const int wv   = t >> 6;

  const int hwBase = hwT << 7;
  const int h0     = hwT << 1;                     // 2 image rows per hw-tile
  const int oBase  = oT << 7;

  // staging: per pass a wave covers 8 rows x 8 slots (1 KB). wave wv owns
  // rows wv*32 + q*8 + (lane>>3), q = 0..3. physical slot = lane&7.
  const int rS = lane >> 3;                        // 0..7
  const int pS = lane & 7;                         // physical 16B slot
  size_t aG[4], bG[4];
  int ldsOff[4];
#pragma unroll
  for (int q = 0; q < 4; ++q) {
    const int row = wv * 32 + q * 8 + rS;
    const int lch = pS ^ (row & 7);                // logical k-chunk (swizzle)
    aG[q] = (size_t)(b * O_ + oBase + row) * KDIM + lch * 8;
    const int hl = row >> 6, wl2 = row & 63;
    bG[q] = ((size_t)(b * XP_H + h0 + hl) * XP_H + wl2) * C_ + lch * 8;
    ldsOff[q] = (wv * 32 + q * 8) * 64;            // shorts
  }

  // fragment geometry (mfma_f32_16x16x32_bf16): A[m=lane&15][k=quad*8+j]
  const int lm   = lane & 15;
  const int quad = lane >> 4;
  const int mW = (wv & 1) << 6;
  const int nW = (wv >> 1) << 6;
  int aOff[2][4], bOff[2][4];
#pragma unroll
  for (int h = 0; h < 2; ++h)
#pragma unroll
    for (int i = 0; i < 4; ++i) {
      const int ps = ((h * 4 + quad) ^ (lm & 7)) * 8;   // de-swizzle, shorts
      aOff[h][i] = (mW + i * 16 + lm) * 64 + ps;
      bOff[h][i] = (nW + i * 16 + lm) * 64 + ps;
    }

  floatx4 acc[4][4] = {};

  for (int tap = 0; tap < 9; ++tap) {
    const int toff = (tap / 3) * XP_H + (tap % 3);      // i*66 + j
#pragma unroll 1
    for (int c0 = 0; c0 < C_; c0 += 64) {
      const int kk = tap * C_ + c0;
      __syncthreads();
#pragma unroll
      for (int q = 0; q < 4; ++q) {
        gld_lds16(wagg + aG[q] + kk, lA + ldsOff[q]);
        gld_lds16(xpad + bG[q] + (size_t)toff * C_ + c0, lB + ldsOff[q]);
      }
      __builtin_amdgcn_s_waitcnt(0x0f70);               // vmcnt(0)
      __syncthreads();

#pragma unroll
      for (int h = 0; h < 2; ++h) {
        short8 af[4], bf[4];
#pragma unroll
        for (int i = 0; i < 4; ++i) af[i] = *(const short8*)(lA + aOff[h][i]);
#pragma unroll
        for (int i = 0; i < 4; ++i) bf[i] = *(const short8*)(lB + bOff[h][i]);
#pragma unroll
        for (int mi = 0; mi < 4; ++mi)
#pragma unroll
          for (int ni = 0; ni < 4; ++ni)
            acc[mi][ni] = __builtin_amdgcn_mfma_f32_16x16x32_bf16(
                af[mi], bf[ni], acc[mi][ni], 0, 0, 0);
      }
    }
  }

  // epilogue: D row = (quad*4 + reg), col = lane&15  [verified m89/m91]
  const size_t outBase = (size_t)b * O_ * HW_;
#pragma unroll
  for (int mi = 0; mi < 4; ++mi) {
#pragma unroll
    for (int ni = 0; ni < 4; ++ni) {
      const int hw = hwBase + nW + ni * 16 + lm;
#pragma unroll
      for (int r = 0; r < 4; ++r) {
        const int o = oBase + mW + mi * 16 + quad * 4 + r;
        out[outBase + (size_t)o * HW_ + hw] = acc[mi][ni][r];
      }
    }
  }
}

// -------------------------------------------------------------- launch ------
extern "C" void kernel_launch(void* const* d_in, const int* in_sizes, int n_in,
                              void* d_out, int out_size, void* d_ws, size_t ws_size,
                              hipStream_t stream) {
  const float* x  = (const float*)d_in[0];   // [32,256,64,64]
  const float* w1 = (const float*)d_in[1];   // [65,256]
  const float* w2 = (const float*)d_in[2];   // [1024,65]
  const float* b2 = (const float*)d_in[3];   // [1024]
  const float* wt = (const float*)d_in[4];   // [4,256,256,3,3]
  float* out = (float*)d_out;                // [32,256,64,64]

  char* ws = (char*)d_ws;
  ushort_t* xpad = (ushort_t*)ws;                                  // 71.4 MB
  ushort_t* wagg = (ushort_t*)(ws + XPAD_ELEMS * 2);               // 37.7 MB
  float* partial = (float*)(ws + XPAD_ELEMS * 2 + WAGG_ELEMS * 2); // 2 MB
  float* attn    = partial + 64 * B_ * C_;                         // 128 KB

  border_kernel<<<B_, 256, 0, stream>>>(xpad);
  pad_kernel<<<dim3(64, 4, B_), 256, 0, stream>>>(x, xpad, partial);
  attn_kernel<<<B_, 256, 0, stream>>>(partial, w1, w2, b2, attn);
  agg_kernel<<<9216, 256, 0, stream>>>(attn, wt, wagg);
  gemm_kernel<<<dim3(32, 2, B_), 256, 0, stream>>>(xpad, wagg, out);
}

// Round 2
// 445.691 us; speedup vs baseline: 1.2408x; 1.2408x over previous
//
#include <hip/hip_runtime.h>
#include <stdint.h>

typedef unsigned short ushort_t;
typedef __attribute__((ext_vector_type(8))) short short8;
typedef __attribute__((ext_vector_type(8))) unsigned short ushortx8;
typedef __attribute__((ext_vector_type(4))) float floatx4;

#define B_    32
#define C_    256
#define O_    256
#define HID_  65
#define HW_   4096
#define KDIM  2304          // C_ * 9
#define XP_H  66            // padded spatial edge
#define XPAD_ELEMS ((size_t)B_ * XP_H * XP_H * C_)   // 35,684,352 bf16
#define WAGG_ELEMS ((size_t)B_ * O_ * KDIM)          // 18,874,368 bf16

static __device__ __forceinline__ unsigned short f2bf(float f) {
  unsigned u = __float_as_uint(f);
  u += 0x7fffu + ((u >> 16) & 1u);        // RNE
  return (unsigned short)(u >> 16);
}

static __device__ __forceinline__ void gld_lds16(const void* g, void* l) {
  // async global->LDS, 16B/lane; LDS dest = wave-uniform base + lane*16
  __builtin_amdgcn_global_load_lds((__attribute__((address_space(1))) void*)(g),
                                   (__attribute__((address_space(3))) void*)(l),
                                   16, 0, 0);
}

// -------------------------------------------------------------- border ------
// zero only the pad borders of xpad (4.3 MB) instead of memsetting 71 MB.
// interior is fully overwritten by pad_kernel.
__global__ void border_kernel(ushort_t* __restrict__ xpad) {
  const int b = blockIdx.x, t = threadIdx.x;
  uint4 z = {0u, 0u, 0u, 0u};
  uint4* base = (uint4*)(xpad + (size_t)b * XP_H * XP_H * C_);
  // row stride = 66*256 shorts = 2112 uint4; w stride = 256 shorts = 32 uint4
  for (int i = t; i < 2112; i += 256) {            // rows h=0 and h=65
    base[i] = z;
    base[(size_t)65 * 2112 + i] = z;
  }
  for (int i = t; i < 64 * 32; i += 256) {         // cols w=0 and w=65, h=1..64
    const int h = 1 + (i >> 5), s = i & 31;
    base[(size_t)h * 2112 + s] = z;
    base[(size_t)h * 2112 + 65 * 32 + s] = z;
  }
}

// ----------------------------------------------------------------- pad ------
// xpad[b][h+1][w+1][c] (bf16, HWC) from x[b][c][h][w] (fp32, CHW), PLUS
// per-block pooling partials: partial[hwT][b*C+c] = sum over this tile's 64 hw.
// float4 loads (16 B/lane), LDS transpose tile [hw][c] (pad 65, all phases
// <=2-way bank alias), ushort8 stores (16 B/lane).
__global__ void pad_kernel(const float* __restrict__ x, ushort_t* __restrict__ xpad,
                           float* __restrict__ partial) {
  __shared__ float tileT[64][65];                  // [hw][c], 16.6 KB
  __shared__ float pool[4][64];
  const int hwT = blockIdx.x, cT = blockIdx.y, b = blockIdx.z;
  const int t = threadIdx.x;
  const int hw0 = hwT * 64, c0 = cT * 64;
  const float* src = x + ((size_t)(b * C_ + c0)) * HW_ + hw0;

  // load: 64c x 64hw = 1024 float4; 4 per thread. lanes sweep hw -> coalesced.
#pragma unroll
  for (int p = 0; p < 4; ++p) {
    const int flat = p * 256 + t;
    const int c = flat >> 4, h4 = (flat & 15) * 4;
    const float4 v = *(const float4*)(src + (size_t)c * HW_ + h4);
    tileT[h4 + 0][c] = v.x;                        // banks: (h4+k+c)%32 -> 2-way
    tileT[h4 + 1][c] = v.y;
    tileT[h4 + 2][c] = v.z;
    tileT[h4 + 3][c] = v.w;
  }
  __syncthreads();

  // pooling: thread owns (qh,c); banks (qh*16+i+c)%32 -> 2-way, free.
  {
    const int c = t & 63, qh = t >> 6;
    float s = 0.f;
#pragma unroll
    for (int i = 0; i < 16; ++i) s += tileT[qh * 16 + i][c];
    pool[qh][c] = s;
  }
  __syncthreads();
  if (t < 64) {
    partial[(size_t)hwT * (B_ * C_) + b * C_ + c0 + t] =
        pool[0][t] + pool[1][t] + pool[2][t] + pool[3][t];
  }

  // store: thread reads 8 consecutive c at one hw (banks hw+cg+j -> 2-way),
  // writes one ushort8 (16 B/lane; 8x128B segments per wave-inst).
#pragma unroll
  for (int p = 0; p < 2; ++p) {
    const int flat = p * 256 + t;
    const int hw = flat >> 3, cg = (flat & 7) * 8;
    ushortx8 v;
#pragma unroll
    for (int j = 0; j < 8; ++j) v[j] = f2bf(tileT[hw][cg + j]);
    const int h = (hw0 + hw) >> 6, w = (hw0 + hw) & 63;
    *(ushortx8*)(xpad + (((size_t)b * XP_H + (h + 1)) * XP_H + (w + 1)) * C_ + c0 + cg) = v;
  }
}

// ---------------------------------------------------------------- attn ------
// one block per b. reduce partials -> pooled; h = relu(pooled@w1^T);
// logits = h@w2^T + b2; softmax over K.
__global__ void attn_kernel(const float* __restrict__ partial,
                            const float* __restrict__ w1,
                            const float* __restrict__ w2,
                            const float* __restrict__ b2,
                            float* __restrict__ attn) {
  __shared__ float sp[C_];
  __shared__ float sh[HID_];
  const int b = blockIdx.x, t = threadIdx.x;
  {
    float s = 0.f;
#pragma unroll
    for (int i = 0; i < 64; ++i) s += partial[(size_t)i * (B_ * C_) + b * C_ + t];
    sp[t] = s * (1.f / 4096.f);
  }
  __syncthreads();
  if (t < HID_) {
    float a = 0.f;
    for (int c = 0; c < C_; ++c) a += sp[c] * w1[t * C_ + c];
    sh[t] = fmaxf(a, 0.f);
  }
  __syncthreads();
  float lg[4];
#pragma unroll
  for (int k = 0; k < 4; ++k) {
    float a = b2[k * O_ + t];
    for (int j = 0; j < HID_; ++j) a += sh[j] * w2[(k * O_ + t) * HID_ + j];
    lg[k] = a * 2.0f;                              // / TEMP (0.5)
  }
  float mx = fmaxf(fmaxf(lg[0], lg[1]), fmaxf(lg[2], lg[3]));
  float e0 = expf(lg[0] - mx), e1 = expf(lg[1] - mx);
  float e2 = expf(lg[2] - mx), e3 = expf(lg[3] - mx);
  float inv = 1.f / (e0 + e1 + e2 + e3);
  attn[(b * 4 + 0) * O_ + t] = e0 * inv;
  attn[(b * 4 + 1) * O_ + t] = e1 * inv;
  attn[(b * 4 + 2) * O_ + t] = e2 * inv;
  attn[(b * 4 + 3) * O_ + t] = e3 * inv;
}

// ----------------------------------------------------------------- agg ------
// wagg[b][o][tap*256+c] = sum_k attn[b,k,o]*weight[k,o,c,tap]
// Register-cached wt (read ONCE per thread: 36 contiguous floats, reused
// across the b-loop — round-1's per-b re-read was the regression) + b-split
// across blockIdx.y for occupancy: 2048 blocks / 8192 waves vs old 1024.
__global__ void agg_kernel(const float* __restrict__ attn,
                           const float* __restrict__ wt,
                           ushort_t* __restrict__ wagg) {
  const int o = blockIdx.x;
  const int b0 = blockIdx.y * 4;                   // 8 groups x 4 b
  const int t = threadIdx.x;                       // = c
  float wr[4][9];
#pragma unroll
  for (int k = 0; k < 4; ++k) {
    const float* src = wt + (size_t)(k * O_ + o) * KDIM + t * 9;
#pragma unroll
    for (int n = 0; n < 9; ++n) wr[k][n] = src[n];
  }
#pragma unroll
  for (int bi = 0; bi < 4; ++bi) {
    const int b = b0 + bi;
    const float a0 = attn[(b * 4 + 0) * O_ + o];
    const float a1 = attn[(b * 4 + 1) * O_ + o];
    const float a2 = attn[(b * 4 + 2) * O_ + o];
    const float a3 = attn[(b * 4 + 3) * O_ + o];
    ushort_t* dst = wagg + (size_t)(b * O_ + o) * KDIM;
#pragma unroll
    for (int n = 0; n < 9; ++n) {
      float v = a0 * wr[0][n] + a1 * wr[1][n] + a2 * wr[2][n] + a3 * wr[3][n];
      dst[n * C_ + t] = f2bf(v);
    }
  }
}

// ---------------------------------------------------------------- gemm ------
// per block: one b, 128-o tile, 128-hw tile. K = 9 taps x 256 c, BK = 64
// (36 K-steps x 32 MFMA). Rows are 64 shorts = 8 slots of 16B; physical
// slot = logical ^ (row & 7) keeps global_load_lds w=16 contiguity and
// <=2-way LDS bank aliasing.
__global__ __launch_bounds__(256) void gemm_kernel(const ushort_t* __restrict__ xpad,
                                                   const ushort_t* __restrict__ wagg,
                                                   float* __restrict__ out) {
  __shared__ short lA[128 * 64];                   // 16 KB
  __shared__ short lB[128 * 64];                   // 16 KB

  const int hwT = blockIdx.x;                      // 0..31
  const int oT  = blockIdx.y;                      // 0..1
  const int b   = blockIdx.z;                      // 0..31
  const int t    = threadIdx.x;
  const int lane = t & 63;
  const int wv   = t >> 6;

  const int hwBase = hwT << 7;
  const int h0     = hwT << 1;                     // 2 image rows per hw-tile
  const int oBase  = oT << 7;

  // staging: per pass a wave covers 8 rows x 8 slots (1 KB). wave wv owns
  // rows wv*32 + q*8 + (lane>>3), q = 0..3. physical slot = lane&7.
  const int rS = lane >> 3;                        // 0..7
  const int pS = lane & 7;                         // physical 16B slot
  size_t aG[4], bG[4];
  int ldsOff[4];
#pragma unroll
  for (int q = 0; q < 4; ++q) {
    const int row = wv * 32 + q * 8 + rS;
    const int lch = pS ^ (row & 7);                // logical k-chunk (swizzle)
    aG[q] = (size_t)(b * O_ + oBase + row) * KDIM + lch * 8;
    const int hl = row >> 6, wl2 = row & 63;
    bG[q] = ((size_t)(b * XP_H + h0 + hl) * XP_H + wl2) * C_ + lch * 8;
    ldsOff[q] = (wv * 32 + q * 8) * 64;            // shorts
  }

  // fragment geometry (mfma_f32_16x16x32_bf16): A[m=lane&15][k=quad*8+j]
  const int lm   = lane & 15;
  const int quad = lane >> 4;
  const int mW = (wv & 1) << 6;
  const int nW = (wv >> 1) << 6;
  int aOff[2][4], bOff[2][4];
#pragma unroll
  for (int h = 0; h < 2; ++h)
#pragma unroll
    for (int i = 0; i < 4; ++i) {
      const int ps = ((h * 4 + quad) ^ (lm & 7)) * 8;   // de-swizzle, shorts
      aOff[h][i] = (mW + i * 16 + lm) * 64 + ps;
      bOff[h][i] = (nW + i * 16 + lm) * 64 + ps;
    }

  floatx4 acc[4][4] = {};

  for (int tap = 0; tap < 9; ++tap) {
    const int toff = (tap / 3) * XP_H + (tap % 3);      // i*66 + j
#pragma unroll 1
    for (int c0 = 0; c0 < C_; c0 += 64) {
      const int kk = tap * C_ + c0;
      __syncthreads();
#pragma unroll
      for (int q = 0; q < 4; ++q) {
        gld_lds16(wagg + aG[q] + kk, lA + ldsOff[q]);
        gld_lds16(xpad + bG[q] + (size_t)toff * C_ + c0, lB + ldsOff[q]);
      }
      __builtin_amdgcn_s_waitcnt(0x0f70);               // vmcnt(0)
      __syncthreads();

#pragma unroll
      for (int h = 0; h < 2; ++h) {
        short8 af[4], bf[4];
#pragma unroll
        for (int i = 0; i < 4; ++i) af[i] = *(const short8*)(lA + aOff[h][i]);
#pragma unroll
        for (int i = 0; i < 4; ++i) bf[i] = *(const short8*)(lB + bOff[h][i]);
#pragma unroll
        for (int mi = 0; mi < 4; ++mi)
#pragma unroll
          for (int ni = 0; ni < 4; ++ni)
            acc[mi][ni] = __builtin_amdgcn_mfma_f32_16x16x32_bf16(
                af[mi], bf[ni], acc[mi][ni], 0, 0, 0);
      }
    }
  }

  // epilogue: D row = (quad*4 + reg), col = lane&15  [verified m89/m91]
  const size_t outBase = (size_t)b * O_ * HW_;
#pragma unroll
  for (int mi = 0; mi < 4; ++mi) {
#pragma unroll
    for (int ni = 0; ni < 4; ++ni) {
      const int hw = hwBase + nW + ni * 16 + lm;
#pragma unroll
      for (int r = 0; r < 4; ++r) {
        const int o = oBase + mW + mi * 16 + quad * 4 + r;
        out[outBase + (size_t)o * HW_ + hw] = acc[mi][ni][r];
      }
    }
  }
}

// -------------------------------------------------------------- launch ------
extern "C" void kernel_launch(void* const* d_in, const int* in_sizes, int n_in,
                              void* d_out, int out_size, void* d_ws, size_t ws_size,
                              hipStream_t stream) {
  const float* x  = (const float*)d_in[0];   // [32,256,64,64]
  const float* w1 = (const float*)d_in[1];   // [65,256]
  const float* w2 = (const float*)d_in[2];   // [1024,65]
  const float* b2 = (const float*)d_in[3];   // [1024]
  const float* wt = (const float*)d_in[4];   // [4,256,256,3,3]
  float* out = (float*)d_out;                // [32,256,64,64]

  char* ws = (char*)d_ws;
  ushort_t* xpad = (ushort_t*)ws;                                  // 71.4 MB
  ushort_t* wagg = (ushort_t*)(ws + XPAD_ELEMS * 2);               // 37.7 MB
  float* partial = (float*)(ws + XPAD_ELEMS * 2 + WAGG_ELEMS * 2); // 2 MB
  float* attn    = partial + 64 * B_ * C_;                         // 128 KB

  border_kernel<<<B_, 256, 0, stream>>>(xpad);
  pad_kernel<<<dim3(64, 4, B_), 256, 0, stream>>>(x, xpad, partial);
  attn_kernel<<<B_, 256, 0, stream>>>(partial, w1, w2, b2, attn);
  agg_kernel<<<dim3(O_, 8), 256, 0, stream>>>(attn, wt, wagg);
  gemm_kernel<<<dim3(32, 2, B_), 256, 0, stream>>>(xpad, wagg, out);
}

// Round 3
// 432.859 us; speedup vs baseline: 1.2775x; 1.0296x over previous
//
#include <hip/hip_runtime.h>
#include <stdint.h>

typedef unsigned short ushort_t;
typedef __attribute__((ext_vector_type(8))) short short8;
typedef __attribute__((ext_vector_type(8))) unsigned short ushortx8;
typedef __attribute__((ext_vector_type(4))) float floatx4;

#define B_    32
#define C_    256
#define O_    256
#define HID_  65
#define HW_   4096
#define KDIM  2304          // C_ * 9
#define XP_H  66            // padded spatial edge
#define XPAD_ELEMS ((size_t)B_ * XP_H * XP_H * C_)   // 35,684,352 bf16
#define WAGG_ELEMS ((size_t)B_ * O_ * KDIM)          // 18,874,368 bf16

static __device__ __forceinline__ unsigned short f2bf(float f) {
  unsigned u = __float_as_uint(f);
  u += 0x7fffu + ((u >> 16) & 1u);        // RNE
  return (unsigned short)(u >> 16);
}

static __device__ __forceinline__ void gld_lds16(const void* g, void* l) {
  // async global->LDS, 16B/lane; LDS dest = wave-uniform base + lane*16
  __builtin_amdgcn_global_load_lds((__attribute__((address_space(1))) void*)(g),
                                   (__attribute__((address_space(3))) void*)(l),
                                   16, 0, 0);
}

// ----------------------------------------------------------------- pad ------
// xpad[b][h+1][w+1][c] (bf16, HWC) from x[b][c][h][w] (fp32, CHW), PLUS
// per-block pooling partials, PLUS (cT==0 blocks) zeroing the pad border
// (fused from the old border_kernel — disjoint region, no ordering needed).
__global__ void pad_kernel(const float* __restrict__ x, ushort_t* __restrict__ xpad,
                           float* __restrict__ partial) {
  __shared__ float tileT[64][65];                  // [hw][c], 16.6 KB
  __shared__ float pool[4][64];
  const int hwT = blockIdx.x, cT = blockIdx.y, b = blockIdx.z;
  const int t = threadIdx.x;
  const int hw0 = hwT * 64, c0 = cT * 64;
  const float* src = x + ((size_t)(b * C_ + c0)) * HW_ + hw0;

  // border fusion: 8320 uint4 per b, spread over the 64 cT==0 blocks.
  if (cT == 0) {
    const int tid = hwT * 256 + t;
    if (tid < 8320) {
      uint4 z = {0u, 0u, 0u, 0u};
      uint4* base = (uint4*)(xpad + (size_t)b * XP_H * XP_H * C_);
      size_t idx;
      if (tid < 2112) idx = (size_t)tid;                               // h=0
      else if (tid < 4224) idx = (size_t)65 * 2112 + (tid - 2112);     // h=65
      else if (tid < 6272) {                                           // w=0
        const int i = tid - 4224;
        idx = (size_t)(1 + (i >> 5)) * 2112 + (i & 31);
      } else {                                                         // w=65
        const int i = tid - 6272;
        idx = (size_t)(1 + (i >> 5)) * 2112 + 65 * 32 + (i & 31);
      }
      base[idx] = z;
    }
  }

  // load: 64c x 64hw = 1024 float4; 4 per thread. lanes sweep hw -> coalesced.
#pragma unroll
  for (int p = 0; p < 4; ++p) {
    const int flat = p * 256 + t;
    const int c = flat >> 4, h4 = (flat & 15) * 4;
    const float4 v = *(const float4*)(src + (size_t)c * HW_ + h4);
    tileT[h4 + 0][c] = v.x;                        // banks: (h4+k+c)%32 -> 2-way
    tileT[h4 + 1][c] = v.y;
    tileT[h4 + 2][c] = v.z;
    tileT[h4 + 3][c] = v.w;
  }
  __syncthreads();

  // pooling: thread owns (qh,c); banks (qh*16+i+c)%32 -> 2-way, free.
  {
    const int c = t & 63, qh = t >> 6;
    float s = 0.f;
#pragma unroll
    for (int i = 0; i < 16; ++i) s += tileT[qh * 16 + i][c];
    pool[qh][c] = s;
  }
  __syncthreads();
  if (t < 64) {
    partial[(size_t)hwT * (B_ * C_) + b * C_ + c0 + t] =
        pool[0][t] + pool[1][t] + pool[2][t] + pool[3][t];
  }

  // store: thread reads 8 consecutive c at one hw (banks hw+cg+j -> 2-way),
  // writes one ushort8 (16 B/lane; 8x128B segments per wave-inst).
#pragma unroll
  for (int p = 0; p < 2; ++p) {
    const int flat = p * 256 + t;
    const int hw = flat >> 3, cg = (flat & 7) * 8;
    ushortx8 v;
#pragma unroll
    for (int j = 0; j < 8; ++j) v[j] = f2bf(tileT[hw][cg + j]);
    const int h = (hw0 + hw) >> 6, w = (hw0 + hw) & 63;
    *(ushortx8*)(xpad + (((size_t)b * XP_H + (h + 1)) * XP_H + (w + 1)) * C_ + c0 + cg) = v;
  }
}

// ---------------------------------------------------------------- attn ------
// one block per b. reduce partials -> pooled; h = relu(pooled@w1^T);
// logits = h@w2^T + b2; softmax over K.
__global__ void attn_kernel(const float* __restrict__ partial,
                            const float* __restrict__ w1,
                            const float* __restrict__ w2,
                            const float* __restrict__ b2,
                            float* __restrict__ attn) {
  __shared__ float sp[C_];
  __shared__ float sh[HID_];
  const int b = blockIdx.x, t = threadIdx.x;
  {
    float s = 0.f;
#pragma unroll
    for (int i = 0; i < 64; ++i) s += partial[(size_t)i * (B_ * C_) + b * C_ + t];
    sp[t] = s * (1.f / 4096.f);
  }
  __syncthreads();
  if (t < HID_) {
    float a = 0.f;
    for (int c = 0; c < C_; ++c) a += sp[c] * w1[t * C_ + c];
    sh[t] = fmaxf(a, 0.f);
  }
  __syncthreads();
  float lg[4];
#pragma unroll
  for (int k = 0; k < 4; ++k) {
    float a = b2[k * O_ + t];
    for (int j = 0; j < HID_; ++j) a += sh[j] * w2[(k * O_ + t) * HID_ + j];
    lg[k] = a * 2.0f;                              // / TEMP (0.5)
  }
  float mx = fmaxf(fmaxf(lg[0], lg[1]), fmaxf(lg[2], lg[3]));
  float e0 = expf(lg[0] - mx), e1 = expf(lg[1] - mx);
  float e2 = expf(lg[2] - mx), e3 = expf(lg[3] - mx);
  float inv = 1.f / (e0 + e1 + e2 + e3);
  attn[(b * 4 + 0) * O_ + t] = e0 * inv;
  attn[(b * 4 + 1) * O_ + t] = e1 * inv;
  attn[(b * 4 + 2) * O_ + t] = e2 * inv;
  attn[(b * 4 + 3) * O_ + t] = e3 * inv;
}

// ----------------------------------------------------------------- agg ------
// wagg[b][o][tap*256+c] = sum_k attn[b,k,o]*weight[k,o,c,tap]
// Register-cached wt (read ONCE per thread: 36 contiguous floats) + b-split
// across blockIdx.y for occupancy: 2048 blocks / 8192 waves.
__global__ void agg_kernel(const float* __restrict__ attn,
                           const float* __restrict__ wt,
                           ushort_t* __restrict__ wagg) {
  const int o = blockIdx.x;
  const int b0 = blockIdx.y * 4;                   // 8 groups x 4 b
  const int t = threadIdx.x;                       // = c
  float wr[4][9];
#pragma unroll
  for (int k = 0; k < 4; ++k) {
    const float* src = wt + (size_t)(k * O_ + o) * KDIM + t * 9;
#pragma unroll
    for (int n = 0; n < 9; ++n) wr[k][n] = src[n];
  }
#pragma unroll
  for (int bi = 0; bi < 4; ++bi) {
    const int b = b0 + bi;
    const float a0 = attn[(b * 4 + 0) * O_ + o];
    const float a1 = attn[(b * 4 + 1) * O_ + o];
    const float a2 = attn[(b * 4 + 2) * O_ + o];
    const float a3 = attn[(b * 4 + 3) * O_ + o];
    ushort_t* dst = wagg + (size_t)(b * O_ + o) * KDIM;
#pragma unroll
    for (int n = 0; n < 9; ++n) {
      float v = a0 * wr[0][n] + a1 * wr[1][n] + a2 * wr[2][n] + a3 * wr[3][n];
      dst[n * C_ + t] = f2bf(v);
    }
  }
}

// ---------------------------------------------------------------- gemm ------
// per block: one b, 128-o tile, 128-hw tile. K = 9 taps x 256 c, BK = 64.
// XCD-group swizzle: linear 2048-block grid decoded so XCD (b&7) owns ALL
// 64 blocks of batch b (both oT x 32 hwT), in q-order — resident working
// set per XCD ~= xpad slice (2.2 MB) + 2 wagg panels (1.2 MB) < 4 MB L2.
// Targets the measured 377 MB FETCH (wagg panels re-fetched by all 8 XCDs).
__global__ __launch_bounds__(256) void gemm_kernel(const ushort_t* __restrict__ xpad,
                                                   const ushort_t* __restrict__ wagg,
                                                   float* __restrict__ out) {
  __shared__ short lA[128 * 64];                   // 16 KB
  __shared__ short lB[128 * 64];                   // 16 KB

  const int bid = blockIdx.x;                      // 0..2047
  const int xcd = bid & 7;                         // HW round-robin heuristic
  const int q   = bid >> 3;                        // 0..255 within XCD
  const int b   = xcd + ((q >> 6) << 3);           // 4 b's per XCD
  const int oT  = (q >> 5) & 1;
  const int hwT = q & 31;

  const int t    = threadIdx.x;
  const int lane = t & 63;
  const int wv   = t >> 6;

  const int hwBase = hwT << 7;
  const int h0     = hwT << 1;                     // 2 image rows per hw-tile
  const int oBase  = oT << 7;

  // staging: per pass a wave covers 8 rows x 8 slots (1 KB). wave wv owns
  // rows wv*32 + q*8 + (lane>>3). physical slot = lane&7.
  const int rS = lane >> 3;                        // 0..7
  const int pS = lane & 7;                         // physical 16B slot
  size_t aG[4], bG[4];
  int ldsOff[4];
#pragma unroll
  for (int qq = 0; qq < 4; ++qq) {
    const int row = wv * 32 + qq * 8 + rS;
    const int lch = pS ^ (row & 7);                // logical k-chunk (swizzle)
    aG[qq] = (size_t)(b * O_ + oBase + row) * KDIM + lch * 8;
    const int hl = row >> 6, wl2 = row & 63;
    bG[qq] = ((size_t)(b * XP_H + h0 + hl) * XP_H + wl2) * C_ + lch * 8;
    ldsOff[qq] = (wv * 32 + qq * 8) * 64;          // shorts
  }

  // fragment geometry (mfma_f32_16x16x32_bf16): A[m=lane&15][k=quad*8+j]
  const int lm   = lane & 15;
  const int quad = lane >> 4;
  const int mW = (wv & 1) << 6;
  const int nW = (wv >> 1) << 6;
  int aOff[2][4], bOff[2][4];
#pragma unroll
  for (int h = 0; h < 2; ++h)
#pragma unroll
    for (int i = 0; i < 4; ++i) {
      const int ps = ((h * 4 + quad) ^ (lm & 7)) * 8;   // de-swizzle, shorts
      aOff[h][i] = (mW + i * 16 + lm) * 64 + ps;
      bOff[h][i] = (nW + i * 16 + lm) * 64 + ps;
    }

  floatx4 acc[4][4] = {};

  for (int tap = 0; tap < 9; ++tap) {
    const int toff = (tap / 3) * XP_H + (tap % 3);      // i*66 + j
#pragma unroll 1
    for (int c0 = 0; c0 < C_; c0 += 64) {
      const int kk = tap * C_ + c0;
      __syncthreads();
#pragma unroll
      for (int qq = 0; qq < 4; ++qq) {
        gld_lds16(wagg + aG[qq] + kk, lA + ldsOff[qq]);
        gld_lds16(xpad + bG[qq] + (size_t)toff * C_ + c0, lB + ldsOff[qq]);
      }
      __builtin_amdgcn_s_waitcnt(0x0f70);               // vmcnt(0)
      __syncthreads();

#pragma unroll
      for (int h = 0; h < 2; ++h) {
        short8 af[4], bf[4];
#pragma unroll
        for (int i = 0; i < 4; ++i) af[i] = *(const short8*)(lA + aOff[h][i]);
#pragma unroll
        for (int i = 0; i < 4; ++i) bf[i] = *(const short8*)(lB + bOff[h][i]);
#pragma unroll
        for (int mi = 0; mi < 4; ++mi)
#pragma unroll
          for (int ni = 0; ni < 4; ++ni)
            acc[mi][ni] = __builtin_amdgcn_mfma_f32_16x16x32_bf16(
                af[mi], bf[ni], acc[mi][ni], 0, 0, 0);
      }
    }
  }

  // epilogue: D row = (quad*4 + reg), col = lane&15  [verified m89/m91]
  const size_t outBase = (size_t)b * O_ * HW_;
#pragma unroll
  for (int mi = 0; mi < 4; ++mi) {
#pragma unroll
    for (int ni = 0; ni < 4; ++ni) {
      const int hw = hwBase + nW + ni * 16 + lm;
#pragma unroll
      for (int r = 0; r < 4; ++r) {
        const int o = oBase + mW + mi * 16 + quad * 4 + r;
        out[outBase + (size_t)o * HW_ + hw] = acc[mi][ni][r];
      }
    }
  }
}

// -------------------------------------------------------------- launch ------
extern "C" void kernel_launch(void* const* d_in, const int* in_sizes, int n_in,
                              void* d_out, int out_size, void* d_ws, size_t ws_size,
                              hipStream_t stream) {
  const float* x  = (const float*)d_in[0];   // [32,256,64,64]
  const float* w1 = (const float*)d_in[1];   // [65,256]
  const float* w2 = (const float*)d_in[2];   // [1024,65]
  const float* b2 = (const float*)d_in[3];   // [1024]
  const float* wt = (const float*)d_in[4];   // [4,256,256,3,3]
  float* out = (float*)d_out;                // [32,256,64,64]

  char* ws = (char*)d_ws;
  ushort_t* xpad = (ushort_t*)ws;                                  // 71.4 MB
  ushort_t* wagg = (ushort_t*)(ws + XPAD_ELEMS * 2);               // 37.7 MB
  float* partial = (float*)(ws + XPAD_ELEMS * 2 + WAGG_ELEMS * 2); // 2 MB
  float* attn    = partial + 64 * B_ * C_;                         // 128 KB

  pad_kernel<<<dim3(64, 4, B_), 256, 0, stream>>>(x, xpad, partial);
  attn_kernel<<<B_, 256, 0, stream>>>(partial, w1, w2, b2, attn);
  agg_kernel<<<dim3(O_, 8), 256, 0, stream>>>(attn, wt, wagg);
  gemm_kernel<<<2048, 256, 0, stream>>>(xpad, wagg, out);
}

// Round 4
// 428.462 us; speedup vs baseline: 1.2906x; 1.0103x over previous
//
#include <hip/hip_runtime.h>
#include <stdint.h>

typedef unsigned short ushort_t;
typedef __attribute__((ext_vector_type(8))) short short8;
typedef __attribute__((ext_vector_type(8))) unsigned short ushortx8;
typedef __attribute__((ext_vector_type(4))) float floatx4;

#define B_    32
#define C_    256
#define O_    256
#define HID_  65
#define HW_   4096
#define KDIM  2304          // C_ * 9
#define XP_H  66            // padded spatial edge
#define XPAD_ELEMS ((size_t)B_ * XP_H * XP_H * C_)   // 35,684,352 bf16
#define WAGG_ELEMS ((size_t)B_ * O_ * KDIM)          // 18,874,368 bf16

static __device__ __forceinline__ unsigned short f2bf(float f) {
  unsigned u = __float_as_uint(f);
  u += 0x7fffu + ((u >> 16) & 1u);        // RNE
  return (unsigned short)(u >> 16);
}

static __device__ __forceinline__ void gld_lds16(const void* g, void* l) {
  // async global->LDS, 16B/lane; LDS dest = wave-uniform base + lane*16
  __builtin_amdgcn_global_load_lds((__attribute__((address_space(1))) void*)(g),
                                   (__attribute__((address_space(3))) void*)(l),
                                   16, 0, 0);
}

// ----------------------------------------------------------------- pad ------
// xpad[b][h+1][w+1][c] (bf16, HWC) from x[b][c][h][w] (fp32, CHW), PLUS
// per-block pooling partials, PLUS (cT==0 blocks) zeroing the pad border.
__global__ void pad_kernel(const float* __restrict__ x, ushort_t* __restrict__ xpad,
                           float* __restrict__ partial) {
  __shared__ float tileT[64][65];                  // [hw][c], 16.6 KB
  __shared__ float pool[4][64];
  const int hwT = blockIdx.x, cT = blockIdx.y, b = blockIdx.z;
  const int t = threadIdx.x;
  const int hw0 = hwT * 64, c0 = cT * 64;
  const float* src = x + ((size_t)(b * C_ + c0)) * HW_ + hw0;

  // border fusion: 8320 uint4 per b, spread over the 64 cT==0 blocks.
  if (cT == 0) {
    const int tid = hwT * 256 + t;
    if (tid < 8320) {
      uint4 z = {0u, 0u, 0u, 0u};
      uint4* base = (uint4*)(xpad + (size_t)b * XP_H * XP_H * C_);
      size_t idx;
      if (tid < 2112) idx = (size_t)tid;                               // h=0
      else if (tid < 4224) idx = (size_t)65 * 2112 + (tid - 2112);     // h=65
      else if (tid < 6272) {                                           // w=0
        const int i = tid - 4224;
        idx = (size_t)(1 + (i >> 5)) * 2112 + (i & 31);
      } else {                                                         // w=65
        const int i = tid - 6272;
        idx = (size_t)(1 + (i >> 5)) * 2112 + 65 * 32 + (i & 31);
      }
      base[idx] = z;
    }
  }

  // load: 64c x 64hw = 1024 float4; 4 per thread. lanes sweep hw -> coalesced.
#pragma unroll
  for (int p = 0; p < 4; ++p) {
    const int flat = p * 256 + t;
    const int c = flat >> 4, h4 = (flat & 15) * 4;
    const float4 v = *(const float4*)(src + (size_t)c * HW_ + h4);
    tileT[h4 + 0][c] = v.x;                        // banks: (h4+k+c)%32 -> 2-way
    tileT[h4 + 1][c] = v.y;
    tileT[h4 + 2][c] = v.z;
    tileT[h4 + 3][c] = v.w;
  }
  __syncthreads();

  // pooling: thread owns (qh,c); banks -> 2-way, free.
  {
    const int c = t & 63, qh = t >> 6;
    float s = 0.f;
#pragma unroll
    for (int i = 0; i < 16; ++i) s += tileT[qh * 16 + i][c];
    pool[qh][c] = s;
  }
  __syncthreads();
  if (t < 64) {
    partial[(size_t)hwT * (B_ * C_) + b * C_ + c0 + t] =
        pool[0][t] + pool[1][t] + pool[2][t] + pool[3][t];
  }

  // store: ushort8 per thread (16 B/lane; 8x128B segments per wave-inst).
#pragma unroll
  for (int p = 0; p < 2; ++p) {
    const int flat = p * 256 + t;
    const int hw = flat >> 3, cg = (flat & 7) * 8;
    ushortx8 v;
#pragma unroll
    for (int j = 0; j < 8; ++j) v[j] = f2bf(tileT[hw][cg + j]);
    const int h = (hw0 + hw) >> 6, w = (hw0 + hw) & 63;
    *(ushortx8*)(xpad + (((size_t)b * XP_H + (h + 1)) * XP_H + (w + 1)) * C_ + c0 + cg) = v;
  }
}

// ---------------------------------------------------------------- attn ------
__global__ void attn_kernel(const float* __restrict__ partial,
                            const float* __restrict__ w1,
                            const float* __restrict__ w2,
                            const float* __restrict__ b2,
                            float* __restrict__ attn) {
  __shared__ float sp[C_];
  __shared__ float sh[HID_];
  const int b = blockIdx.x, t = threadIdx.x;
  {
    float s = 0.f;
#pragma unroll
    for (int i = 0; i < 64; ++i) s += partial[(size_t)i * (B_ * C_) + b * C_ + t];
    sp[t] = s * (1.f / 4096.f);
  }
  __syncthreads();
  if (t < HID_) {
    float a = 0.f;
    for (int c = 0; c < C_; ++c) a += sp[c] * w1[t * C_ + c];
    sh[t] = fmaxf(a, 0.f);
  }
  __syncthreads();
  float lg[4];
#pragma unroll
  for (int k = 0; k < 4; ++k) {
    float a = b2[k * O_ + t];
    for (int j = 0; j < HID_; ++j) a += sh[j] * w2[(k * O_ + t) * HID_ + j];
    lg[k] = a * 2.0f;                              // / TEMP (0.5)
  }
  float mx = fmaxf(fmaxf(lg[0], lg[1]), fmaxf(lg[2], lg[3]));
  float e0 = expf(lg[0] - mx), e1 = expf(lg[1] - mx);
  float e2 = expf(lg[2] - mx), e3 = expf(lg[3] - mx);
  float inv = 1.f / (e0 + e1 + e2 + e3);
  attn[(b * 4 + 0) * O_ + t] = e0 * inv;
  attn[(b * 4 + 1) * O_ + t] = e1 * inv;
  attn[(b * 4 + 2) * O_ + t] = e2 * inv;
  attn[(b * 4 + 3) * O_ + t] = e3 * inv;
}

// ----------------------------------------------------------------- agg ------
// Register-cached wt (36 contiguous floats/thread) + b-split for occupancy.
__global__ void agg_kernel(const float* __restrict__ attn,
                           const float* __restrict__ wt,
                           ushort_t* __restrict__ wagg) {
  const int o = blockIdx.x;
  const int b0 = blockIdx.y * 4;                   // 8 groups x 4 b
  const int t = threadIdx.x;                       // = c
  float wr[4][9];
#pragma unroll
  for (int k = 0; k < 4; ++k) {
    const float* src = wt + (size_t)(k * O_ + o) * KDIM + t * 9;
#pragma unroll
    for (int n = 0; n < 9; ++n) wr[k][n] = src[n];
  }
#pragma unroll
  for (int bi = 0; bi < 4; ++bi) {
    const int b = b0 + bi;
    const float a0 = attn[(b * 4 + 0) * O_ + o];
    const float a1 = attn[(b * 4 + 1) * O_ + o];
    const float a2 = attn[(b * 4 + 2) * O_ + o];
    const float a3 = attn[(b * 4 + 3) * O_ + o];
    ushort_t* dst = wagg + (size_t)(b * O_ + o) * KDIM;
#pragma unroll
    for (int n = 0; n < 9; ++n) {
      float v = a0 * wr[0][n] + a1 * wr[1][n] + a2 * wr[2][n] + a3 * wr[3][n];
      dst[n * C_ + t] = f2bf(v);
    }
  }
}

// ---------------------------------------------------------------- gemm ------
// 256(o) x 256(hw) tile, 8 waves (2M x 4N), BK=64, double-buffered 128 KiB
// LDS, counted-vmcnt pipeline (T3+T4): per K-tile t —
//   compute(buf t&1) ; s_barrier ; stage tile t+2 -> buf t&1 ;
//   s_waitcnt vmcnt(8)  [= tile t+1's 8 loads retired, t+2's in flight] ;
//   s_barrier.
// Raw s_barrier (NOT __syncthreads: that re-inserts the vmcnt(0) drain).
// sched_barrier(0) fences keep ds_reads inside their buffer's live window.
// Row swizzle: physical 16B slot = logical ^ (row&7), linear LDS dest +
// inverse-swizzled global source + swizzled read (both-sides rule).
__global__ __launch_bounds__(512) void gemm_kernel(const ushort_t* __restrict__ xpad,
                                                   const ushort_t* __restrict__ wagg,
                                                   float* __restrict__ out) {
  __shared__ short lA0[2 * 256 * 64];              // 64 KB (2 bufs)
  __shared__ short lB0[2 * 256 * 64];              // 64 KB

  // XCD-group decode: xcd (bid&7) owns all 16 hw-tiles of 4 b's.
  const int bid = blockIdx.x;                      // 0..511
  const int xcd = bid & 7;
  const int q   = bid >> 3;                        // 0..63
  const int b   = xcd + ((q >> 4) << 3);
  const int hwT = q & 15;                          // 16 hw tiles of 256
  const int hwBase = hwT << 8;
  const int h0     = hwT << 2;                     // 4 image rows per tile

  const int t    = threadIdx.x;
  const int lane = t & 63;
  const int wv   = t >> 6;                         // 0..7

  // staging: per issue a wave covers 8 rows x 8 slots (1 KB); 4 issues cover
  // rows [wv*32, wv*32+32) of the 256-row tile; 8 issues (A+B) per K-tile.
  const int rS  = lane >> 3;                       // 0..7
  const int pS  = lane & 7;                        // physical 16B slot
  const int lch = pS ^ rS;                         // logical k-chunk (row&7==rS)
  size_t aG[4], bG[4];
  int ldsOff[4];
#pragma unroll
  for (int j = 0; j < 4; ++j) {
    const int row = wv * 32 + j * 8 + rS;
    aG[j] = (size_t)(b * O_ + row) * KDIM + lch * 8;
    const int hl = row >> 6, wl2 = row & 63;
    bG[j] = ((size_t)(b * XP_H + h0 + hl) * XP_H + wl2) * C_ + lch * 8;
    ldsOff[j] = (wv * 32 + j * 8) * 64;            // shorts
  }

  // fragment geometry (mfma_f32_16x16x32_bf16)
  const int lm   = lane & 15;
  const int quad = lane >> 4;
  const int wr   = wv >> 2;                        // 0..1 (M)
  const int wc   = wv & 3;                         // 0..3 (N)
  const int mW   = wr << 7;                        // o base (wave): 0/128
  const int nW   = wc << 6;                        // hw base (wave): 0..192
  int aBase[2], bBase[2];
#pragma unroll
  for (int h = 0; h < 2; ++h) {
    const int ps = ((h * 4 + quad) ^ (lm & 7)) * 8;     // de-swizzle, shorts
    aBase[h] = (mW + lm) * 64 + ps;
    bBase[h] = (nW + lm) * 64 + ps;
  }

  floatx4 acc[8][4] = {};

  // prologue: stage tile0 -> buf0, tile1 -> buf1 (tap 0, c0 = 0 / 64)
#pragma unroll
  for (int j = 0; j < 4; ++j) {
    gld_lds16(wagg + aG[j], lA0 + ldsOff[j]);
    gld_lds16(xpad + bG[j], lB0 + ldsOff[j]);
  }
#pragma unroll
  for (int j = 0; j < 4; ++j) {
    gld_lds16(wagg + aG[j] + 64, lA0 + 16384 + ldsOff[j]);
    gld_lds16(xpad + bG[j] + 64, lB0 + 16384 + ldsOff[j]);
  }
  __builtin_amdgcn_s_waitcnt(0x0f78);              // vmcnt(8): tile0 landed
  __builtin_amdgcn_s_barrier();
  __builtin_amdgcn_sched_barrier(0);

  // K-loop: 36 K-tiles (kt = tap*4 + c-quarter), tile kt in buf kt&1
#pragma unroll 1
  for (int tt = 0; tt < 36; ++tt) {
    const int cb = (tt & 1) * 16384;
    const short* bufA = lA0 + cb;
    const short* bufB = lB0 + cb;
#pragma unroll
    for (int h = 0; h < 2; ++h) {
      short8 af[8], bf[4];
#pragma unroll
      for (int i = 0; i < 8; ++i) af[i] = *(const short8*)(bufA + aBase[h] + i * 1024);
#pragma unroll
      for (int i = 0; i < 4; ++i) bf[i] = *(const short8*)(bufB + bBase[h] + i * 1024);
      __builtin_amdgcn_s_setprio(1);
#pragma unroll
      for (int mi = 0; mi < 8; ++mi)
#pragma unroll
        for (int ni = 0; ni < 4; ++ni)
          acc[mi][ni] = __builtin_amdgcn_mfma_f32_16x16x32_bf16(
              af[mi], bf[ni], acc[mi][ni], 0, 0, 0);
      __builtin_amdgcn_s_setprio(0);
    }
    if (tt == 35) break;
    __builtin_amdgcn_sched_barrier(0);
    __builtin_amdgcn_s_barrier();                  // reads of buf cb done
    if (tt + 2 < 36) {
      const int kt  = tt + 2;                      // -> buf kt&1 == tt&1 (cb)
      const int tap = kt >> 2;
      const size_t aK = (size_t)kt << 6;           // kt*64 shorts
      const size_t bK = (size_t)((tap / 3) * XP_H + (tap % 3)) * C_ + ((kt & 3) << 6);
      short* dA = lA0 + cb;
      short* dB = lB0 + cb;
#pragma unroll
      for (int j = 0; j < 4; ++j) {
        gld_lds16(wagg + aG[j] + aK, dA + ldsOff[j]);
        gld_lds16(xpad + bG[j] + bK, dB + ldsOff[j]);
      }
      __builtin_amdgcn_s_waitcnt(0x0f78);          // vmcnt(8): tile tt+1 ready
    } else {
      __builtin_amdgcn_s_waitcnt(0x0f70);          // vmcnt(0): last tile ready
    }
    __builtin_amdgcn_s_barrier();                  // buf cb^1 visible to all
    __builtin_amdgcn_sched_barrier(0);
  }

  // epilogue: D row(o) = quad*4 + r, col(hw) = lane&15  [verified m89/m91]
  const size_t outBase = (size_t)b * O_ * HW_;
#pragma unroll
  for (int mi = 0; mi < 8; ++mi) {
#pragma unroll
    for (int ni = 0; ni < 4; ++ni) {
      const int hw = hwBase + nW + ni * 16 + lm;
#pragma unroll
      for (int r = 0; r < 4; ++r) {
        const int o = mW + mi * 16 + quad * 4 + r;
        out[outBase + (size_t)o * HW_ + hw] = acc[mi][ni][r];
      }
    }
  }
}

// -------------------------------------------------------------- launch ------
extern "C" void kernel_launch(void* const* d_in, const int* in_sizes, int n_in,
                              void* d_out, int out_size, void* d_ws, size_t ws_size,
                              hipStream_t stream) {
  const float* x  = (const float*)d_in[0];   // [32,256,64,64]
  const float* w1 = (const float*)d_in[1];   // [65,256]
  const float* w2 = (const float*)d_in[2];   // [1024,65]
  const float* b2 = (const float*)d_in[3];   // [1024]
  const float* wt = (const float*)d_in[4];   // [4,256,256,3,3]
  float* out = (float*)d_out;                // [32,256,64,64]

  char* ws = (char*)d_ws;
  ushort_t* xpad = (ushort_t*)ws;                                  // 71.4 MB
  ushort_t* wagg = (ushort_t*)(ws + XPAD_ELEMS * 2);               // 37.7 MB
  float* partial = (float*)(ws + XPAD_ELEMS * 2 + WAGG_ELEMS * 2); // 2 MB
  float* attn    = partial + 64 * B_ * C_;                         // 128 KB

  pad_kernel<<<dim3(64, 4, B_), 256, 0, stream>>>(x, xpad, partial);
  attn_kernel<<<B_, 256, 0, stream>>>(partial, w1, w2, b2, attn);
  agg_kernel<<<dim3(O_, 8), 256, 0, stream>>>(attn, wt, wagg);
  gemm_kernel<<<512, 512, 0, stream>>>(xpad, wagg, out);
}

// Round 5
// 426.216 us; speedup vs baseline: 1.2975x; 1.0053x over previous
//
#include <hip/hip_runtime.h>
#include <stdint.h>

typedef unsigned short ushort_t;
typedef __attribute__((ext_vector_type(8))) short short8;
typedef __attribute__((ext_vector_type(8))) unsigned short ushortx8;
typedef __attribute__((ext_vector_type(4))) float floatx4;

#define B_    32
#define C_    256
#define O_    256
#define HID_  65
#define HW_   4096
#define KDIM  2304          // C_ * 9
#define XP_H  66            // padded spatial edge
#define XPAD_ELEMS ((size_t)B_ * XP_H * XP_H * C_)   // 35,684,352 bf16
#define WAGG_ELEMS ((size_t)B_ * O_ * KDIM)          // 18,874,368 bf16

static __device__ __forceinline__ unsigned short f2bf(float f) {
  unsigned u = __float_as_uint(f);
  u += 0x7fffu + ((u >> 16) & 1u);        // RNE
  return (unsigned short)(u >> 16);
}

static __device__ __forceinline__ void gld_lds16(const void* g, void* l) {
  // async global->LDS, 16B/lane; LDS dest = wave-uniform base + lane*16
  __builtin_amdgcn_global_load_lds((__attribute__((address_space(1))) void*)(g),
                                   (__attribute__((address_space(3))) void*)(l),
                                   16, 0, 0);
}

#define FENCE() __builtin_amdgcn_sched_barrier(0)
#define BAR()   __builtin_amdgcn_s_barrier()
#define LGKM0() __builtin_amdgcn_s_waitcnt(0xC07F)   // lgkmcnt(0), vm/exp ignored

// ----------------------------------------------------------------- pad ------
// xpad[b][h+1][w+1][c] (bf16, HWC) from x[b][c][h][w] (fp32, CHW), PLUS
// per-block pooling partials, PLUS (cT==0 blocks) zeroing the pad border.
__global__ void pad_kernel(const float* __restrict__ x, ushort_t* __restrict__ xpad,
                           float* __restrict__ partial) {
  __shared__ float tileT[64][65];                  // [hw][c], 16.6 KB
  __shared__ float pool[4][64];
  const int hwT = blockIdx.x, cT = blockIdx.y, b = blockIdx.z;
  const int t = threadIdx.x;
  const int hw0 = hwT * 64, c0 = cT * 64;
  const float* src = x + ((size_t)(b * C_ + c0)) * HW_ + hw0;

  // border fusion: 8320 uint4 per b, spread over the 64 cT==0 blocks.
  if (cT == 0) {
    const int tid = hwT * 256 + t;
    if (tid < 8320) {
      uint4 z = {0u, 0u, 0u, 0u};
      uint4* base = (uint4*)(xpad + (size_t)b * XP_H * XP_H * C_);
      size_t idx;
      if (tid < 2112) idx = (size_t)tid;                               // h=0
      else if (tid < 4224) idx = (size_t)65 * 2112 + (tid - 2112);     // h=65
      else if (tid < 6272) {                                           // w=0
        const int i = tid - 4224;
        idx = (size_t)(1 + (i >> 5)) * 2112 + (i & 31);
      } else {                                                         // w=65
        const int i = tid - 6272;
        idx = (size_t)(1 + (i >> 5)) * 2112 + 65 * 32 + (i & 31);
      }
      base[idx] = z;
    }
  }

  // load: 64c x 64hw = 1024 float4; 4 per thread. lanes sweep hw -> coalesced.
#pragma unroll
  for (int p = 0; p < 4; ++p) {
    const int flat = p * 256 + t;
    const int c = flat >> 4, h4 = (flat & 15) * 4;
    const float4 v = *(const float4*)(src + (size_t)c * HW_ + h4);
    tileT[h4 + 0][c] = v.x;                        // banks -> 2-way, free
    tileT[h4 + 1][c] = v.y;
    tileT[h4 + 2][c] = v.z;
    tileT[h4 + 3][c] = v.w;
  }
  __syncthreads();

  // pooling: thread owns (qh,c); banks -> 2-way, free.
  {
    const int c = t & 63, qh = t >> 6;
    float s = 0.f;
#pragma unroll
    for (int i = 0; i < 16; ++i) s += tileT[qh * 16 + i][c];
    pool[qh][c] = s;
  }
  __syncthreads();
  if (t < 64) {
    partial[(size_t)hwT * (B_ * C_) + b * C_ + c0 + t] =
        pool[0][t] + pool[1][t] + pool[2][t] + pool[3][t];
  }

  // store: ushort8 per thread (16 B/lane; 8x128B segments per wave-inst).
#pragma unroll
  for (int p = 0; p < 2; ++p) {
    const int flat = p * 256 + t;
    const int hw = flat >> 3, cg = (flat & 7) * 8;
    ushortx8 v;
#pragma unroll
    for (int j = 0; j < 8; ++j) v[j] = f2bf(tileT[hw][cg + j]);
    const int h = (hw0 + hw) >> 6, w = (hw0 + hw) & 63;
    *(ushortx8*)(xpad + (((size_t)b * XP_H + (h + 1)) * XP_H + (w + 1)) * C_ + c0 + cg) = v;
  }
}

// ---------------------------------------------------------------- attn ------
__global__ void attn_kernel(const float* __restrict__ partial,
                            const float* __restrict__ w1,
                            const float* __restrict__ w2,
                            const float* __restrict__ b2,
                            float* __restrict__ attn) {
  __shared__ float sp[C_];
  __shared__ float sh[HID_];
  const int b = blockIdx.x, t = threadIdx.x;
  {
    float s = 0.f;
#pragma unroll
    for (int i = 0; i < 64; ++i) s += partial[(size_t)i * (B_ * C_) + b * C_ + t];
    sp[t] = s * (1.f / 4096.f);
  }
  __syncthreads();
  if (t < HID_) {
    float a = 0.f;
    for (int c = 0; c < C_; ++c) a += sp[c] * w1[t * C_ + c];
    sh[t] = fmaxf(a, 0.f);
  }
  __syncthreads();
  float lg[4];
#pragma unroll
  for (int k = 0; k < 4; ++k) {
    float a = b2[k * O_ + t];
    for (int j = 0; j < HID_; ++j) a += sh[j] * w2[(k * O_ + t) * HID_ + j];
    lg[k] = a * 2.0f;                              // / TEMP (0.5)
  }
  float mx = fmaxf(fmaxf(lg[0], lg[1]), fmaxf(lg[2], lg[3]));
  float e0 = expf(lg[0] - mx), e1 = expf(lg[1] - mx);
  float e2 = expf(lg[2] - mx), e3 = expf(lg[3] - mx);
  float inv = 1.f / (e0 + e1 + e2 + e3);
  attn[(b * 4 + 0) * O_ + t] = e0 * inv;
  attn[(b * 4 + 1) * O_ + t] = e1 * inv;
  attn[(b * 4 + 2) * O_ + t] = e2 * inv;
  attn[(b * 4 + 3) * O_ + t] = e3 * inv;
}

// ----------------------------------------------------------------- agg ------
// Register-cached wt (36 contiguous floats/thread) + b-split for occupancy.
__global__ void agg_kernel(const float* __restrict__ attn,
                           const float* __restrict__ wt,
                           ushort_t* __restrict__ wagg) {
  const int o = blockIdx.x;
  const int b0 = blockIdx.y * 4;                   // 8 groups x 4 b
  const int t = threadIdx.x;                       // = c
  float wr[4][9];
#pragma unroll
  for (int k = 0; k < 4; ++k) {
    const float* src = wt + (size_t)(k * O_ + o) * KDIM + t * 9;
#pragma unroll
    for (int n = 0; n < 9; ++n) wr[k][n] = src[n];
  }
#pragma unroll
  for (int bi = 0; bi < 4; ++bi) {
    const int b = b0 + bi;
    const float a0 = attn[(b * 4 + 0) * O_ + o];
    const float a1 = attn[(b * 4 + 1) * O_ + o];
    const float a2 = attn[(b * 4 + 2) * O_ + o];
    const float a3 = attn[(b * 4 + 3) * O_ + o];
    ushort_t* dst = wagg + (size_t)(b * O_ + o) * KDIM;
#pragma unroll
    for (int n = 0; n < 9; ++n) {
      float v = a0 * wr[0][n] + a1 * wr[1][n] + a2 * wr[2][n] + a3 * wr[3][n];
      dst[n * C_ + t] = f2bf(v);
    }
  }
}

// ---------------------------------------------------------------- gemm ------
// 256(o) x 256(hw), BK=64, 8 waves (2M x 4N), dbuf 128 KiB LDS, true
// fine-grained 4-phase/K-tile schedule (m201 port):
//   p0: ds af(mi0-3,h0)+bf(h0) | stage tt+1 {A1,A3}->other | BAR lgkm MFMA BAR
//   p1: ds af(mi4-7,h0)                                    | BAR lgkm MFMA BAR
//   p2: ds af(mi0-3,h1)+bf(h1)                             | BAR lgkm MFMA BAR
//   p3: ds af(mi4-7,h1) | stage tt+2 {A0,A2,B0-3}->this    | BAR lgkm MFMA
//       vmcnt(6) BAR   [vmcnt never drains to 0 mid-loop]
// Region safety: stage calls are row-contiguous 64-row blocks; {A0,A2,B}'s
// last reads complete at p2's barrier (written p3); {A1,A3}'s at p3's
// barrier (written next tile's p0, other buffer). Tile v's 8 loads = 6 at
// (v-2)p3 + 2 at (v-1)p0 -> vmcnt(6) at (v-1)p3 retires exactly v's.
__global__ __launch_bounds__(512) void gemm_kernel(const ushort_t* __restrict__ xpad,
                                                   const ushort_t* __restrict__ wagg,
                                                   float* __restrict__ out) {
  __shared__ short lA0[2 * 256 * 64];              // 64 KB (2 bufs)
  __shared__ short lB0[2 * 256 * 64];              // 64 KB

  const int bid = blockIdx.x;                      // 0..511
  const int xcd = bid & 7;
  const int q   = bid >> 3;
  const int b   = xcd + ((q >> 4) << 3);
  const int hwT = q & 15;
  const int hwBase = hwT << 8;
  const int h0     = hwT << 2;                     // 4 image rows per tile

  const int t    = threadIdx.x;
  const int lane = t & 63;
  const int wv   = t >> 6;                         // 0..7

  // staging: call j covers contiguous rows [j*64, j*64+64); wave wv owns
  // rows j*64 + wv*8 + rS. physical 16B slot = pS, logical chunk = pS^rS.
  const int rS  = lane >> 3;
  const int pS  = lane & 7;
  const int lch = pS ^ rS;                         // row&7 == rS for all calls
  size_t aG2[4], bG2[4];
  int sOff[4];
#pragma unroll
  for (int j = 0; j < 4; ++j) {
    const int row = j * 64 + wv * 8 + rS;
    aG2[j] = (size_t)(b * O_ + row) * KDIM + lch * 8;
    bG2[j] = ((size_t)(b * XP_H + h0 + j) * XP_H + (wv * 8 + rS)) * C_ + lch * 8;
    sOff[j] = (j * 64 + wv * 8) * 64;              // shorts
  }

  // fragment geometry (mfma_f32_16x16x32_bf16)
  const int lm   = lane & 15;
  const int quad = lane >> 4;
  const int mW   = (wv >> 2) << 7;                 // o base: 0/128
  const int nW   = (wv & 3) << 6;                  // hw base: 0..192
  int aBase[2], bBase[2];
#pragma unroll
  for (int h = 0; h < 2; ++h) {
    const int ps = ((h * 4 + quad) ^ (lm & 7)) * 8;     // de-swizzle, shorts
    aBase[h] = (mW + lm) * 64 + ps;
    bBase[h] = (nW + lm) * 64 + ps;
  }

  auto stageA = [&](int j, int kt, short* dst) {
    gld_lds16(wagg + aG2[j] + ((size_t)kt << 6), dst + sOff[j]);
  };
  auto stageB = [&](int j, int kt, short* dst) {
    const int tap = kt >> 2;
    const size_t off = (size_t)((tap / 3) * XP_H + (tap % 3)) * C_ + ((kt & 3) << 6);
    gld_lds16(xpad + bG2[j] + off, dst + sOff[j]);
  };

  floatx4 acc[8][4] = {};

  // ---- prologue: tile0 full (8 calls) -> buf0; tile1 {A0,A2,B0-3} -> buf1
#pragma unroll
  for (int j = 0; j < 4; ++j) {
    stageA(j, 0, lA0);
    stageB(j, 0, lB0);
  }
  stageA(0, 1, lA0 + 16384);
  stageA(2, 1, lA0 + 16384);
#pragma unroll
  for (int j = 0; j < 4; ++j) stageB(j, 1, lB0 + 16384);
  __builtin_amdgcn_s_waitcnt(0x0f76);              // vmcnt(6): tile0 landed
  BAR();
  FENCE();

#pragma unroll 1
  for (int tt = 0; tt < 36; ++tt) {
    const int cb = (tt & 1) << 14;                 // buffer offset (shorts)
    const short* bufA = lA0 + cb;
    const short* bufB = lB0 + cb;
    short* oA = lA0 + (cb ^ 16384);
    short8 af[4], bf[4];

    // -------- p0: af(mi0-3,h0)+bf(h0); stage tt+1 {A1,A3} -> other --------
#pragma unroll
    for (int i = 0; i < 4; ++i) af[i] = *(const short8*)(bufA + aBase[0] + i * 1024);
#pragma unroll
    for (int i = 0; i < 4; ++i) bf[i] = *(const short8*)(bufB + bBase[0] + i * 1024);
    if (tt < 35) {
      stageA(1, tt + 1, oA);
      stageA(3, tt + 1, oA);
    }
    FENCE(); BAR(); LGKM0(); FENCE();
    __builtin_amdgcn_s_setprio(1);
#pragma unroll
    for (int mi = 0; mi < 4; ++mi)
#pragma unroll
      for (int ni = 0; ni < 4; ++ni)
        acc[mi][ni] = __builtin_amdgcn_mfma_f32_16x16x32_bf16(af[mi], bf[ni], acc[mi][ni], 0, 0, 0);
    __builtin_amdgcn_s_setprio(0);
    FENCE(); BAR(); FENCE();

    // -------- p1: af(mi4-7,h0) ------------------------------------------
#pragma unroll
    for (int i = 0; i < 4; ++i) af[i] = *(const short8*)(bufA + aBase[0] + (4 + i) * 1024);
    FENCE(); BAR(); LGKM0(); FENCE();
    __builtin_amdgcn_s_setprio(1);
#pragma unroll
    for (int mi = 0; mi < 4; ++mi)
#pragma unroll
      for (int ni = 0; ni < 4; ++ni)
        acc[4 + mi][ni] = __builtin_amdgcn_mfma_f32_16x16x32_bf16(af[mi], bf[ni], acc[4 + mi][ni], 0, 0, 0);
    __builtin_amdgcn_s_setprio(0);
    FENCE(); BAR(); FENCE();

    // -------- p2: af(mi0-3,h1)+bf(h1) -----------------------------------
#pragma unroll
    for (int i = 0; i < 4; ++i) af[i] = *(const short8*)(bufA + aBase[1] + i * 1024);
#pragma unroll
    for (int i = 0; i < 4; ++i) bf[i] = *(const short8*)(bufB + bBase[1] + i * 1024);
    FENCE(); BAR(); LGKM0(); FENCE();
    __builtin_amdgcn_s_setprio(1);
#pragma unroll
    for (int mi = 0; mi < 4; ++mi)
#pragma unroll
      for (int ni = 0; ni < 4; ++ni)
        acc[mi][ni] = __builtin_amdgcn_mfma_f32_16x16x32_bf16(af[mi], bf[ni], acc[mi][ni], 0, 0, 0);
    __builtin_amdgcn_s_setprio(0);
    FENCE(); BAR(); FENCE();

    // -------- p3: af(mi4-7,h1); stage tt+2 {A0,A2,B0-3} -> this buf ------
#pragma unroll
    for (int i = 0; i < 4; ++i) af[i] = *(const short8*)(bufA + aBase[1] + (4 + i) * 1024);
    if (tt < 34) {
      stageA(0, tt + 2, lA0 + cb);
      stageA(2, tt + 2, lA0 + cb);
#pragma unroll
      for (int j = 0; j < 4; ++j) stageB(j, tt + 2, lB0 + cb);
    }
    FENCE(); BAR(); LGKM0(); FENCE();
    __builtin_amdgcn_s_setprio(1);
#pragma unroll
    for (int mi = 0; mi < 4; ++mi)
#pragma unroll
      for (int ni = 0; ni < 4; ++ni)
        acc[4 + mi][ni] = __builtin_amdgcn_mfma_f32_16x16x32_bf16(af[mi], bf[ni], acc[4 + mi][ni], 0, 0, 0);
    __builtin_amdgcn_s_setprio(0);
    FENCE();
    if (tt < 34)      __builtin_amdgcn_s_waitcnt(0x0f76);  // vmcnt(6)
    else if (tt == 34) __builtin_amdgcn_s_waitcnt(0x0f70); // vmcnt(0)
    if (tt < 35) { BAR(); FENCE(); }
  }

  // epilogue: D row(o) = quad*4 + r, col(hw) = lane&15  [verified m89/m91]
  const size_t outBase = (size_t)b * O_ * HW_;
#pragma unroll
  for (int mi = 0; mi < 8; ++mi) {
#pragma unroll
    for (int ni = 0; ni < 4; ++ni) {
      const int hw = hwBase + nW + ni * 16 + lm;
#pragma unroll
      for (int r = 0; r < 4; ++r) {
        const int o = mW + mi * 16 + quad * 4 + r;
        out[outBase + (size_t)o * HW_ + hw] = acc[mi][ni][r];
      }
    }
  }
}

// -------------------------------------------------------------- launch ------
extern "C" void kernel_launch(void* const* d_in, const int* in_sizes, int n_in,
                              void* d_out, int out_size, void* d_ws, size_t ws_size,
                              hipStream_t stream) {
  const float* x  = (const float*)d_in[0];   // [32,256,64,64]
  const float* w1 = (const float*)d_in[1];   // [65,256]
  const float* w2 = (const float*)d_in[2];   // [1024,65]
  const float* b2 = (const float*)d_in[3];   // [1024]
  const float* wt = (const float*)d_in[4];   // [4,256,256,3,3]
  float* out = (float*)d_out;                // [32,256,64,64]

  char* ws = (char*)d_ws;
  ushort_t* xpad = (ushort_t*)ws;                                  // 71.4 MB
  ushort_t* wagg = (ushort_t*)(ws + XPAD_ELEMS * 2);               // 37.7 MB
  float* partial = (float*)(ws + XPAD_ELEMS * 2 + WAGG_ELEMS * 2); // 2 MB
  float* attn    = partial + 64 * B_ * C_;                         // 128 KB

  pad_kernel<<<dim3(64, 4, B_), 256, 0, stream>>>(x, xpad, partial);
  attn_kernel<<<B_, 256, 0, stream>>>(partial, w1, w2, b2, attn);
  agg_kernel<<<dim3(O_, 8), 256, 0, stream>>>(attn, wt, wagg);
  gemm_kernel<<<512, 512, 0, stream>>>(xpad, wagg, out);
}